// Round 1
// baseline (173.517 us; speedup 1.0000x reference)
//
#include <hip/hip_runtime.h>
#include <hip/hip_bf16.h>

// Problem constants (fixed by the reference): B=16, V=8192, N=2048, H=128, C_OUT=7
#define B_GR   16
#define V_PTS  8192
#define N_RES  2048
#define H_DIM  128
#define C_OUT  7
#define SEGS   16            // pool kernel: residue segments per graph (128 residues each)

// argmin decomposition
#define NSPLIT 16                    // residue splits per graph
#define NL     (N_RES / NSPLIT)      // 128 residues per block
#define VPT    8                     // vertices per thread (4 packed pairs)
#define NP     (VPT / 2)             // fp32x2 vertex pairs per thread
#define VBLK   (256 * VPT)           // 2048 vertices per block
#define VBLKS  (V_PTS / VBLK)        // 4 vertex-blocks per graph
// grid = B * VBLKS * NSPLIT = 16*4*16 = 1024 blocks -> 4 blocks/CU, 16 waves/CU

typedef float f32x2 __attribute__((ext_vector_type(2)));

// last-block-done counter for the fused pool+mlp kernel.
// zero-initialized at module load; the last arriving block resets it to 0,
// so every graph replay starts from a clean state without a memset node.
__device__ unsigned int g_cnt[B_GR];

// ---------------------------------------------------------------------------
// Kernel 1: partial nearest-residue argmin over a 128-residue slice, 8
// vertices per thread, processed as 4 packed fp32 pairs (VOP3P v_pk_*_f32).
// Bit-exact replication of the reference fp32 sequence per 32-bit half:
//   d = fadd( fma(-2, dot, vsq), csq ),  dot = fadd(fadd(x*cx, y*cy), z*cz)
// v_pk_{mul,add,fma}_f32 are IEEE RN fp32 per half (same MODE register as
// scalar VALU), so every comparison is bit-identical to the scalar version.
// The shared residue value is broadcast into both halves with op_sel /
// op_sel_hi instead of splat v_movs:
//   broadcast src1.lo: op_sel:[0,0] op_sel_hi:[1,0]
//   broadcast src1.hi: op_sel:[0,1] op_sel_hi:[1,1]
// (c.x,c.y) and (c.z,c.w) are free aligned sub-pairs of the ds_read_b128 quad.
// Instruction count: 13 per 2 pairs (7 pk + 2 cmp + 4 cndmask) vs 20 scalar.
// Partials merged across splits with atomicMin on packed
// (monotone-flipped dist bits << 32) | global_idx — unchanged from baseline.
// ---------------------------------------------------------------------------
__global__ __launch_bounds__(256, 4) void k_argmin(const float* __restrict__ verts,
                                                   const float* __restrict__ coords,
                                                   unsigned long long* __restrict__ mi64) {
    __shared__ float4 sc[NL];                          // 2 KB
    const int b  = blockIdx.x / (VBLKS * NSPLIT);
    const int r  = blockIdx.x % (VBLKS * NSPLIT);
    const int vb = r / NSPLIT;
    const int ns = r % NSPLIT;

    const float* cbase = coords + ((size_t)b * N_RES + ns * NL) * 3;
    if (threadIdx.x < NL) {
        const int i = threadIdx.x;
        float x = cbase[i * 3 + 0];
        float y = cbase[i * 3 + 1];
        float z = cbase[i * 3 + 2];
        float csq = __fadd_rn(__fadd_rn(__fmul_rn(x, x), __fmul_rn(y, y)), __fmul_rn(z, z));
        sc[i] = make_float4(x, y, z, csq);
    }
    __syncthreads();

    const int vbase = vb * VBLK + threadIdx.x;         // vertex index within graph
    const float* vp = verts + (size_t)b * V_PTS * 3;

    f32x2 vx2[NP], vy2[NP], vz2[NP], vq2[NP];
    float best[VPT];
    int bi[VPT];
#pragma unroll
    for (int j = 0; j < NP; ++j) {
#pragma unroll
        for (int h = 0; h < 2; ++h) {
            const int k = 2 * j + h;
            const int v = vbase + k * 256;
            float x = vp[v * 3 + 0];
            float y = vp[v * 3 + 1];
            float z = vp[v * 3 + 2];
            vx2[j][h] = x;
            vy2[j][h] = y;
            vz2[j][h] = z;
            vq2[j][h] = __fadd_rn(__fadd_rn(__fmul_rn(x, x), __fmul_rn(y, y)),
                                  __fmul_rn(z, z));
            best[k] = 3.402823466e+38f;
            bi[k] = 0;
        }
    }

    const f32x2 neg2 = {-2.0f, -2.0f};                 // hoisted constant pair

    // unroll 2: n stays a uniform (SGPR) value -> cndmask can take it directly.
#pragma unroll 2
    for (int n = 0; n < NL; ++n) {
        const float4 c = sc[n];
        f32x2 cxy, czw;
        cxy.x = c.x; cxy.y = c.y;                      // sub-pair of the b128 quad
        czw.x = c.z; czw.y = c.w;
#pragma unroll
        for (int j = 0; j < NP; ++j) {
            f32x2 m0, m1, m2, s0, dot, e, d;
            asm("v_pk_mul_f32 %0, %1, %2 op_sel:[0,0] op_sel_hi:[1,0]"
                : "=v"(m0) : "v"(vx2[j]), "v"(cxy));   // (vx0*cx, vx1*cx)
            asm("v_pk_mul_f32 %0, %1, %2 op_sel:[0,1] op_sel_hi:[1,1]"
                : "=v"(m1) : "v"(vy2[j]), "v"(cxy));   // (vy0*cy, vy1*cy)
            asm("v_pk_add_f32 %0, %1, %2"
                : "=v"(s0) : "v"(m0), "v"(m1));
            asm("v_pk_mul_f32 %0, %1, %2 op_sel:[0,0] op_sel_hi:[1,0]"
                : "=v"(m2) : "v"(vz2[j]), "v"(czw));   // (vz0*cz, vz1*cz)
            asm("v_pk_add_f32 %0, %1, %2"
                : "=v"(dot) : "v"(s0), "v"(m2));       // exact fadd(fadd(.,.),.)
            asm("v_pk_fma_f32 %0, %1, %2, %3"
                : "=v"(e) : "v"(neg2), "v"(dot), "v"(vq2[j]));  // fma(-2,dot,vsq)
            asm("v_pk_add_f32 %0, %1, %2 op_sel:[0,1] op_sel_hi:[1,1]"
                : "=v"(d) : "v"(e), "v"(czw));         // + csq (broadcast c.w)

            const int k0 = 2 * j, k1 = 2 * j + 1;
            bool mlo = d.x < best[k0];                 // strict <: first index wins
            best[k0] = mlo ? d.x : best[k0];
            bi[k0]   = mlo ? n : bi[k0];
            bool mhi = d.y < best[k1];
            best[k1] = mhi ? d.y : best[k1];
            bi[k1]   = mhi ? n : bi[k1];
        }
    }

#pragma unroll
    for (int k = 0; k < VPT; ++k) {
        unsigned int bits = __float_as_uint(best[k]);
        unsigned int key  = bits ^ (unsigned int)(((int)bits >> 31) | 0x80000000);
        unsigned long long packed =
            ((unsigned long long)key << 32) | (unsigned int)(ns * NL + bi[k]);
        atomicMin(&mi64[(size_t)b * V_PTS + vbase + k * 256], packed);
    }
}

// ---------------------------------------------------------------------------
// Kernel 2 (fused pool + mlp): rebuild per-graph hit mask in LDS from packed
// argmin, masked-sum a 128-residue slice of feats with float4 loads, write
// per-seg partials; the LAST block of each graph (device-scope atomic counter
// + release/acquire threadfence) then reduces the 16 partials and runs the
// tiny MLP. Saves the separate 16-block k_mlp launch.
// ---------------------------------------------------------------------------
__global__ __launch_bounds__(256) void k_pool_mlp(const unsigned long long* __restrict__ mi64,
                                                  const float* __restrict__ feats,
                                                  const float* __restrict__ W1,
                                                  const float* __restrict__ b1,
                                                  const float* __restrict__ W2,
                                                  const float* __restrict__ b2,
                                                  float* __restrict__ partial,
                                                  float* __restrict__ out) {
    __shared__ float msk[N_RES];                        // 8 KB
    __shared__ float4 red[8][32];
    __shared__ unsigned int slast;
    __shared__ float pooled[H_DIM];
    __shared__ float h1[H_DIM];
    const int b   = blockIdx.x >> 4;
    const int seg = blockIdx.x & (SEGS - 1);

    for (int i = threadIdx.x; i < N_RES; i += 256) msk[i] = 0.0f;
    __syncthreads();

    const unsigned long long* mb = mi64 + (size_t)b * V_PTS;
    for (int v = threadIdx.x; v < V_PTS; v += 256)
        msk[(unsigned int)mb[v]] = 1.0f;                // race benign: all write 1
    __syncthreads();

    const int q = threadIdx.x & 31;                     // float4 column (h = 4q..4q+3)
    const int s = threadIdx.x >> 5;                     // n-slice 0..7
    const int n0 = seg * (N_RES / SEGS);
    const float4* fb4 = (const float4*)(feats + ((size_t)b * N_RES + n0) * H_DIM);

    float4 acc = make_float4(0.f, 0.f, 0.f, 0.f);
#pragma unroll
    for (int n = 0; n < N_RES / SEGS / 8; ++n) {
        const int nn = s + n * 8;
        const float m = msk[n0 + nn];
        const float4 f = fb4[(size_t)nn * 32 + q];
        acc.x = fmaf(f.x, m, acc.x);
        acc.y = fmaf(f.y, m, acc.y);
        acc.z = fmaf(f.z, m, acc.z);
        acc.w = fmaf(f.w, m, acc.w);
    }
    red[s][q] = acc;
    __syncthreads();

    if (s == 0) {
        float4 t = acc;
#pragma unroll
        for (int i = 1; i < 8; ++i) {
            t.x += red[i][q].x; t.y += red[i][q].y;
            t.z += red[i][q].z; t.w += red[i][q].w;
        }
        ((float4*)partial)[((size_t)b * SEGS + seg) * 32 + q] = t;
    }

    // ---- last-block-done: release our partial, count arrivals ----
    __threadfence();                                    // release partial writes
    __syncthreads();                                    // writers' fences done
    if (threadIdx.x == 0) {
        unsigned int old = atomicAdd(&g_cnt[b], 1u);    // device scope
        unsigned int lastf = (old == SEGS - 1) ? 1u : 0u;
        if (lastf) g_cnt[b] = 0u;                       // reset for next replay
        slast = lastf;
    }
    __syncthreads();
    if (!slast) return;

    // ---- last block: reduce partials -> pooled, relu MLP -> out[b][7] ----
    __threadfence();                                    // acquire others' partials
    const int j = threadIdx.x;
    if (j < H_DIM) {
        float sum = 0.0f;
#pragma unroll
        for (int g = 0; g < SEGS; ++g)
            sum += partial[((size_t)b * SEGS + g) * H_DIM + j];
        pooled[j] = sum;
    }
    __syncthreads();
    if (j < H_DIM) {
        float a1 = b1[j];
#pragma unroll 8
        for (int hh = 0; hh < H_DIM; ++hh)
            a1 = fmaf(pooled[hh], W1[hh * H_DIM + j], a1);
        h1[j] = fmaxf(a1, 0.0f);
    }
    __syncthreads();
    if (j < C_OUT) {
        float o = b2[j];
#pragma unroll 8
        for (int hh = 0; hh < H_DIM; ++hh)
            o = fmaf(h1[hh], W2[hh * C_OUT + j], o);
        out[(size_t)b * C_OUT + j] = o;
    }
}

extern "C" void kernel_launch(void* const* d_in, const int* in_sizes, int n_in,
                              void* d_out, int out_size, void* d_ws, size_t ws_size,
                              hipStream_t stream) {
    const float* verts  = (const float*)d_in[0];   // [B,V,3]
    const float* coords = (const float*)d_in[1];   // [B,N,3]
    const float* feats  = (const float*)d_in[2];   // [B,N,H]
    const float* W1     = (const float*)d_in[3];   // [H,H]
    const float* b1     = (const float*)d_in[4];   // [H]
    const float* W2     = (const float*)d_in[5];   // [H,C_OUT]
    const float* b2     = (const float*)d_in[6];   // [C_OUT]
    float* out = (float*)d_out;                    // [B,C_OUT]

    // workspace layout (unchanged)
    unsigned long long* mi64 = (unsigned long long*)d_ws;                 // B*V u64 = 1 MB
    float* partial = (float*)((char*)d_ws + (size_t)B_GR * V_PTS * 8);    // B*SEGS*H = 128 KB

    hipMemsetAsync(mi64, 0xFF, (size_t)B_GR * V_PTS * 8, stream);         // graph-legal memset node
    k_argmin  <<<B_GR * VBLKS * NSPLIT, 256, 0, stream>>>(verts, coords, mi64);
    k_pool_mlp<<<B_GR * SEGS,           256, 0, stream>>>(mi64, feats, W1, b1, W2, b2,
                                                          partial, out);
}

// Round 2
// 152.151 us; speedup vs baseline: 1.1404x; 1.1404x over previous
//
#include <hip/hip_runtime.h>
#include <hip/hip_bf16.h>

// Problem constants (fixed by the reference): B=16, V=8192, N=2048, H=128, C_OUT=7
#define B_GR   16
#define V_PTS  8192
#define N_RES  2048
#define H_DIM  128
#define C_OUT  7
#define SEGS   16            // pool kernel: residue segments per graph (128 residues each)

// argmin decomposition
#define NSPLIT 16                    // residue splits per graph
#define NL     (N_RES / NSPLIT)      // 128 residues per block
#define VPT    4                     // vertices per thread (4 independent FMA chains)
#define VBLK   (256 * VPT)           // 1024 vertices per block
#define VBLKS  (V_PTS / VBLK)        // 8 vertex-blocks per graph
// grid = B * VBLKS * NSPLIT = 16*8*16 = 2048 blocks -> 8 blocks/CU, 32 waves/CU.
// Round-1 lesson: v_pk_*_f32 is NOT double-rate on CDNA4 (64-bit datapath per
// lane = two SIMD passes), so the win here is TLP, not packed math.

// ---------------------------------------------------------------------------
// Kernel 1: partial nearest-residue argmin over a 128-residue slice, 4
// vertices per thread. Bit-exact replication of the reference fp32 sequence:
//   d = fadd( fma(-2, dot, vsq), csq ),  dot = fadd(fadd(x*cx, y*cy), z*cz)
// (fma(-2,dot,vsq) == RN(vsq - 2*dot) exactly since 2*dot is exact.)
// Partials merged across splits with atomicMin on packed
// (monotone-flipped dist bits << 32) | global_idx  — equal dists pick the
// smaller index, matching np.argmin first-occurrence. d == -0.0 impossible
// (csq >= +0), so the flip transform's -0<+0 quirk never triggers.
// ---------------------------------------------------------------------------
__global__ __launch_bounds__(256, 8) void k_argmin(const float* __restrict__ verts,
                                                   const float* __restrict__ coords,
                                                   unsigned long long* __restrict__ mi64) {
    __shared__ float4 sc[NL];                          // 2 KB
    const int b  = blockIdx.x / (VBLKS * NSPLIT);
    const int r  = blockIdx.x % (VBLKS * NSPLIT);
    const int vb = r / NSPLIT;
    const int ns = r % NSPLIT;

    const float* cbase = coords + ((size_t)b * N_RES + ns * NL) * 3;
    if (threadIdx.x < NL) {
        const int i = threadIdx.x;
        float x = cbase[i * 3 + 0];
        float y = cbase[i * 3 + 1];
        float z = cbase[i * 3 + 2];
        float csq = __fadd_rn(__fadd_rn(__fmul_rn(x, x), __fmul_rn(y, y)), __fmul_rn(z, z));
        sc[i] = make_float4(x, y, z, csq);
    }
    __syncthreads();

    const int vbase = vb * VBLK + threadIdx.x;         // vertex index within graph
    const float* vp = verts + (size_t)b * V_PTS * 3;

    float vx[VPT], vy[VPT], vz[VPT], vsq[VPT], best[VPT];
    int bi[VPT];
#pragma unroll
    for (int k = 0; k < VPT; ++k) {
        const int v = vbase + k * 256;
        vx[k] = vp[v * 3 + 0];
        vy[k] = vp[v * 3 + 1];
        vz[k] = vp[v * 3 + 2];
        vsq[k] = __fadd_rn(__fadd_rn(__fmul_rn(vx[k], vx[k]), __fmul_rn(vy[k], vy[k])),
                           __fmul_rn(vz[k], vz[k]));
        best[k] = 3.402823466e+38f;
        bi[k] = 0;
    }

    // unroll 4: n stays a uniform (SGPR) value -> cndmask can take it directly,
    // and the ds_read_b128s batch ahead of their waits.
#pragma unroll 4
    for (int n = 0; n < NL; ++n) {
        const float4 c = sc[n];
#pragma unroll
        for (int k = 0; k < VPT; ++k) {
            float dot = __fadd_rn(__fadd_rn(__fmul_rn(vx[k], c.x), __fmul_rn(vy[k], c.y)),
                                  __fmul_rn(vz[k], c.z));
            float d = __fadd_rn(fmaf(-2.0f, dot, vsq[k]), c.w);
            bool m = d < best[k];                      // strict <: first index wins
            best[k] = m ? d : best[k];
            bi[k]   = m ? n : bi[k];
        }
    }

#pragma unroll
    for (int k = 0; k < VPT; ++k) {
        unsigned int bits = __float_as_uint(best[k]);
        unsigned int key  = bits ^ (unsigned int)(((int)bits >> 31) | 0x80000000);
        unsigned long long packed =
            ((unsigned long long)key << 32) | (unsigned int)(ns * NL + bi[k]);
        atomicMin(&mi64[(size_t)b * V_PTS + vbase + k * 256], packed);
    }
}

// ---------------------------------------------------------------------------
// Kernel 2: rebuild per-graph hit mask in LDS from packed argmin (low 32 bits
// = index), masked-sum a 128-residue slice of feats with float4 loads.
// Grid: B*SEGS = 256 blocks, 256 threads: lane-quad q=tid&31 covers H=128 as
// float4; slice s=tid>>5 gives 8-way n-parallelism, LDS-reduced at the end.
// ---------------------------------------------------------------------------
__global__ __launch_bounds__(256) void k_pool(const unsigned long long* __restrict__ mi64,
                                              const float* __restrict__ feats,
                                              float* __restrict__ partial) {
    __shared__ float msk[N_RES];                        // 8 KB
    __shared__ float4 red[8][32];
    const int b   = blockIdx.x >> 4;
    const int seg = blockIdx.x & (SEGS - 1);

    for (int i = threadIdx.x; i < N_RES; i += 256) msk[i] = 0.0f;
    __syncthreads();

    const unsigned long long* mb = mi64 + (size_t)b * V_PTS;
    for (int v = threadIdx.x; v < V_PTS; v += 256)
        msk[(unsigned int)mb[v]] = 1.0f;                // race benign: all write 1
    __syncthreads();

    const int q = threadIdx.x & 31;                     // float4 column (h = 4q..4q+3)
    const int s = threadIdx.x >> 5;                     // n-slice 0..7
    const int n0 = seg * (N_RES / SEGS);
    const float4* fb4 = (const float4*)(feats + ((size_t)b * N_RES + n0) * H_DIM);

    float4 acc = make_float4(0.f, 0.f, 0.f, 0.f);
#pragma unroll
    for (int n = 0; n < N_RES / SEGS / 8; ++n) {
        const int nn = s + n * 8;
        const float m = msk[n0 + nn];
        const float4 f = fb4[(size_t)nn * 32 + q];
        acc.x = fmaf(f.x, m, acc.x);
        acc.y = fmaf(f.y, m, acc.y);
        acc.z = fmaf(f.z, m, acc.z);
        acc.w = fmaf(f.w, m, acc.w);
    }
    red[s][q] = acc;
    __syncthreads();

    if (s == 0) {
        float4 t = acc;
#pragma unroll
        for (int i = 1; i < 8; ++i) {
            t.x += red[i][q].x; t.y += red[i][q].y;
            t.z += red[i][q].z; t.w += red[i][q].w;
        }
        ((float4*)partial)[((size_t)b * SEGS + seg) * 32 + q] = t;
    }
}

// ---------------------------------------------------------------------------
// Kernel 3: per-graph block — reduce 16 seg partials -> pooled[H], then
// relu(pooled@W1+b1)@W2+b2 -> out[b][7]. 16 blocks x 128 threads.
// (Round-1 lesson: fusing this into k_pool via last-block-done costs ~19 µs —
// __threadfence() is a device-scope release -> per-block L2 writeback on
// non-coherent XCD L2s. Separate tiny launch is cheaper.)
// ---------------------------------------------------------------------------
__global__ __launch_bounds__(128) void k_mlp(const float* __restrict__ partial,
                                             const float* __restrict__ W1,
                                             const float* __restrict__ b1,
                                             const float* __restrict__ W2,
                                             const float* __restrict__ b2,
                                             float* __restrict__ out) {
    __shared__ float pooled[H_DIM];
    __shared__ float h1[H_DIM];
    const int b = blockIdx.x;
    const int j = threadIdx.x;

    float s = 0.0f;
#pragma unroll
    for (int g = 0; g < SEGS; ++g)
        s += partial[((size_t)b * SEGS + g) * H_DIM + j];
    pooled[j] = s;
    __syncthreads();

    float acc = b1[j];
#pragma unroll 8
    for (int hh = 0; hh < H_DIM; ++hh)
        acc = fmaf(pooled[hh], W1[hh * H_DIM + j], acc);
    h1[j] = fmaxf(acc, 0.0f);
    __syncthreads();

    if (j < C_OUT) {
        float o = b2[j];
#pragma unroll 8
        for (int hh = 0; hh < H_DIM; ++hh)
            o = fmaf(h1[hh], W2[hh * C_OUT + j], o);
        out[(size_t)b * C_OUT + j] = o;
    }
}

extern "C" void kernel_launch(void* const* d_in, const int* in_sizes, int n_in,
                              void* d_out, int out_size, void* d_ws, size_t ws_size,
                              hipStream_t stream) {
    const float* verts  = (const float*)d_in[0];   // [B,V,3]
    const float* coords = (const float*)d_in[1];   // [B,N,3]
    const float* feats  = (const float*)d_in[2];   // [B,N,H]
    const float* W1     = (const float*)d_in[3];   // [H,H]
    const float* b1     = (const float*)d_in[4];   // [H]
    const float* W2     = (const float*)d_in[5];   // [H,C_OUT]
    const float* b2     = (const float*)d_in[6];   // [C_OUT]
    float* out = (float*)d_out;                    // [B,C_OUT]

    // workspace layout
    unsigned long long* mi64 = (unsigned long long*)d_ws;                 // B*V u64 = 1 MB
    float* partial = (float*)((char*)d_ws + (size_t)B_GR * V_PTS * 8);    // B*SEGS*H = 128 KB

    hipMemsetAsync(mi64, 0xFF, (size_t)B_GR * V_PTS * 8, stream);         // graph-legal memset node
    k_argmin<<<B_GR * VBLKS * NSPLIT, 256, 0, stream>>>(verts, coords, mi64);
    k_pool  <<<B_GR * SEGS,           256, 0, stream>>>(mi64, feats, partial);
    k_mlp   <<<B_GR,                  128, 0, stream>>>(partial, W1, b1, W2, b2, out);
}

// Round 3
// 146.375 us; speedup vs baseline: 1.1854x; 1.0395x over previous
//
#include <hip/hip_runtime.h>
#include <hip/hip_bf16.h>

// Problem constants (fixed by the reference): B=16, V=8192, N=2048, H=128, C_OUT=7
#define B_GR   16
#define V_PTS  8192
#define N_RES  2048
#define H_DIM  128
#define C_OUT  7
#define SEGS   16            // pool kernel: residue segments per graph (128 residues each)

// argmin decomposition (round-0 geometry: best measured instruction diet)
#define NSPLIT 16                    // residue splits per graph
#define NL     (N_RES / NSPLIT)      // 128 residues per block
#define VPT    8                     // vertices per thread (8 independent FMA chains)
#define VBLK   (256 * VPT)           // 2048 vertices per block
#define VBLKS  (V_PTS / VBLK)        // 4 vertex-blocks per graph
// grid = B * VBLKS * NSPLIT = 1024 blocks.
// Round-1 lesson: v_pk_*_f32 is NOT double-rate on CDNA4 -> scalar VALU.
// Round-2 lesson: occupancy 26->47% left dur flat at VALUBusy~80% -> issue-
// bound, not latency-bound. This round removes the device-scope atomicMin
// merge (2M RMWs, 16 per address across XCDs) in favor of plain stores + a
// separate min-reduce kernel.

// ---------------------------------------------------------------------------
// Kernel 1 (store path): partial nearest-residue argmin over a 128-residue
// slice, 8 vertices per thread. Bit-exact replication of the reference fp32
// sequence:
//   d = fadd( fma(-2, dot, vsq), csq ),  dot = fadd(fadd(x*cx, y*cy), z*cz)
// Per-split winner written with a plain coalesced store of packed
// (monotone-flipped dist bits << 32) | global_idx; cross-split merge happens
// in k_merge. Equal dists pick the smaller index (u64 <), matching np.argmin
// first-occurrence.
// ---------------------------------------------------------------------------
__global__ __launch_bounds__(256, 4) void k_argmin_st(const float* __restrict__ verts,
                                                      const float* __restrict__ coords,
                                                      unsigned long long* __restrict__ part) {
    __shared__ float4 sc[NL];                          // 2 KB
    const int b  = blockIdx.x / (VBLKS * NSPLIT);
    const int r  = blockIdx.x % (VBLKS * NSPLIT);
    const int vb = r / NSPLIT;
    const int ns = r % NSPLIT;

    const float* cbase = coords + ((size_t)b * N_RES + ns * NL) * 3;
    if (threadIdx.x < NL) {
        const int i = threadIdx.x;
        float x = cbase[i * 3 + 0];
        float y = cbase[i * 3 + 1];
        float z = cbase[i * 3 + 2];
        float csq = __fadd_rn(__fadd_rn(__fmul_rn(x, x), __fmul_rn(y, y)), __fmul_rn(z, z));
        sc[i] = make_float4(x, y, z, csq);
    }
    __syncthreads();

    const int vbase = vb * VBLK + threadIdx.x;         // vertex index within graph
    const float* vp = verts + (size_t)b * V_PTS * 3;

    float vx[VPT], vy[VPT], vz[VPT], vsq[VPT], best[VPT];
    int bi[VPT];
#pragma unroll
    for (int k = 0; k < VPT; ++k) {
        const int v = vbase + k * 256;
        vx[k] = vp[v * 3 + 0];
        vy[k] = vp[v * 3 + 1];
        vz[k] = vp[v * 3 + 2];
        vsq[k] = __fadd_rn(__fadd_rn(__fmul_rn(vx[k], vx[k]), __fmul_rn(vy[k], vy[k])),
                           __fmul_rn(vz[k], vz[k]));
        best[k] = 3.402823466e+38f;
        bi[k] = 0;
    }

    // unroll 2: n stays a uniform (SGPR) value -> cndmask can take it directly.
#pragma unroll 2
    for (int n = 0; n < NL; ++n) {
        const float4 c = sc[n];
#pragma unroll
        for (int k = 0; k < VPT; ++k) {
            float dot = __fadd_rn(__fadd_rn(__fmul_rn(vx[k], c.x), __fmul_rn(vy[k], c.y)),
                                  __fmul_rn(vz[k], c.z));
            float d = __fadd_rn(fmaf(-2.0f, dot, vsq[k]), c.w);
            bool m = d < best[k];                      // strict <: first index wins
            best[k] = m ? d : best[k];
            bi[k]   = m ? n : bi[k];
        }
    }

    unsigned long long* op = part + ((size_t)(b * NSPLIT + ns)) * V_PTS + vbase;
#pragma unroll
    for (int k = 0; k < VPT; ++k) {
        unsigned int bits = __float_as_uint(best[k]);
        unsigned int key  = bits ^ (unsigned int)(((int)bits >> 31) | 0x80000000);
        unsigned long long packed =
            ((unsigned long long)key << 32) | (unsigned int)(ns * NL + bi[k]);
        op[k * 256] = packed;                          // plain coalesced store
    }
}

// ---------------------------------------------------------------------------
// Kernel 1b (merge): per-vertex min over the 16 per-split candidates, then
// scatter the winning residue into the global hit mask (race-benign 1.0f
// stores). 512 blocks x 256 threads; 16 coalesced u64 loads per thread.
// ---------------------------------------------------------------------------
__global__ __launch_bounds__(256) void k_merge(const unsigned long long* __restrict__ part,
                                               float* __restrict__ msk) {
    const int gv = blockIdx.x * 256 + threadIdx.x;     // 0 .. B*V-1
    const int b  = gv >> 13;                           // / V_PTS
    const int v  = gv & (V_PTS - 1);

    const unsigned long long* p = part + (size_t)b * NSPLIT * V_PTS + v;
    unsigned long long c[NSPLIT];
#pragma unroll
    for (int s = 0; s < NSPLIT; ++s)                   // batch all loads first
        c[s] = p[(size_t)s * V_PTS];
    unsigned long long best = c[0];
#pragma unroll
    for (int s = 1; s < NSPLIT; ++s)
        best = c[s] < best ? c[s] : best;              // u64 <: idx breaks ties

    msk[b * N_RES + (unsigned int)best] = 1.0f;        // low 32 bits = global idx
}

// ---------------------------------------------------------------------------
// Kernel 2 (store path): masked-sum a 128-residue slice of feats with float4
// loads; mask slice staged from the tiny global msk array (512 B).
// Grid: B*SEGS = 256 blocks, 256 threads: lane-quad q=tid&31 covers H=128 as
// float4; slice s=tid>>5 gives 8-way n-parallelism, LDS-reduced at the end.
// ---------------------------------------------------------------------------
__global__ __launch_bounds__(256) void k_pool_m(const float* __restrict__ msk,
                                                const float* __restrict__ feats,
                                                float* __restrict__ partial) {
    __shared__ float sm[NL];                            // 512 B mask slice
    __shared__ float4 red[8][32];
    const int b   = blockIdx.x >> 4;
    const int seg = blockIdx.x & (SEGS - 1);
    const int n0  = seg * (N_RES / SEGS);               // N_RES/SEGS == NL == 128

    if (threadIdx.x < NL) sm[threadIdx.x] = msk[b * N_RES + n0 + threadIdx.x];
    __syncthreads();

    const int q = threadIdx.x & 31;                     // float4 column (h = 4q..4q+3)
    const int s = threadIdx.x >> 5;                     // n-slice 0..7
    const float4* fb4 = (const float4*)(feats + ((size_t)b * N_RES + n0) * H_DIM);

    float4 acc = make_float4(0.f, 0.f, 0.f, 0.f);
#pragma unroll
    for (int n = 0; n < N_RES / SEGS / 8; ++n) {
        const int nn = s + n * 8;
        const float m = sm[nn];
        const float4 f = fb4[(size_t)nn * 32 + q];
        acc.x = fmaf(f.x, m, acc.x);
        acc.y = fmaf(f.y, m, acc.y);
        acc.z = fmaf(f.z, m, acc.z);
        acc.w = fmaf(f.w, m, acc.w);
    }
    red[s][q] = acc;
    __syncthreads();

    if (s == 0) {
        float4 t = acc;
#pragma unroll
        for (int i = 1; i < 8; ++i) {
            t.x += red[i][q].x; t.y += red[i][q].y;
            t.z += red[i][q].z; t.w += red[i][q].w;
        }
        ((float4*)partial)[((size_t)b * SEGS + seg) * 32 + q] = t;
    }
}

// ---------------------------------------------------------------------------
// Fallback path (small workspace): round-0 atomicMin kernels, verbatim.
// ---------------------------------------------------------------------------
__global__ __launch_bounds__(256, 4) void k_argmin_at(const float* __restrict__ verts,
                                                      const float* __restrict__ coords,
                                                      unsigned long long* __restrict__ mi64) {
    __shared__ float4 sc[NL];
    const int b  = blockIdx.x / (VBLKS * NSPLIT);
    const int r  = blockIdx.x % (VBLKS * NSPLIT);
    const int vb = r / NSPLIT;
    const int ns = r % NSPLIT;

    const float* cbase = coords + ((size_t)b * N_RES + ns * NL) * 3;
    if (threadIdx.x < NL) {
        const int i = threadIdx.x;
        float x = cbase[i * 3 + 0];
        float y = cbase[i * 3 + 1];
        float z = cbase[i * 3 + 2];
        float csq = __fadd_rn(__fadd_rn(__fmul_rn(x, x), __fmul_rn(y, y)), __fmul_rn(z, z));
        sc[i] = make_float4(x, y, z, csq);
    }
    __syncthreads();

    const int vbase = vb * VBLK + threadIdx.x;
    const float* vp = verts + (size_t)b * V_PTS * 3;

    float vx[VPT], vy[VPT], vz[VPT], vsq[VPT], best[VPT];
    int bi[VPT];
#pragma unroll
    for (int k = 0; k < VPT; ++k) {
        const int v = vbase + k * 256;
        vx[k] = vp[v * 3 + 0];
        vy[k] = vp[v * 3 + 1];
        vz[k] = vp[v * 3 + 2];
        vsq[k] = __fadd_rn(__fadd_rn(__fmul_rn(vx[k], vx[k]), __fmul_rn(vy[k], vy[k])),
                           __fmul_rn(vz[k], vz[k]));
        best[k] = 3.402823466e+38f;
        bi[k] = 0;
    }
#pragma unroll 2
    for (int n = 0; n < NL; ++n) {
        const float4 c = sc[n];
#pragma unroll
        for (int k = 0; k < VPT; ++k) {
            float dot = __fadd_rn(__fadd_rn(__fmul_rn(vx[k], c.x), __fmul_rn(vy[k], c.y)),
                                  __fmul_rn(vz[k], c.z));
            float d = __fadd_rn(fmaf(-2.0f, dot, vsq[k]), c.w);
            bool m = d < best[k];
            best[k] = m ? d : best[k];
            bi[k]   = m ? n : bi[k];
        }
    }
#pragma unroll
    for (int k = 0; k < VPT; ++k) {
        unsigned int bits = __float_as_uint(best[k]);
        unsigned int key  = bits ^ (unsigned int)(((int)bits >> 31) | 0x80000000);
        unsigned long long packed =
            ((unsigned long long)key << 32) | (unsigned int)(ns * NL + bi[k]);
        atomicMin(&mi64[(size_t)b * V_PTS + vbase + k * 256], packed);
    }
}

__global__ __launch_bounds__(256) void k_pool_at(const unsigned long long* __restrict__ mi64,
                                                 const float* __restrict__ feats,
                                                 float* __restrict__ partial) {
    __shared__ float msk[N_RES];
    __shared__ float4 red[8][32];
    const int b   = blockIdx.x >> 4;
    const int seg = blockIdx.x & (SEGS - 1);

    for (int i = threadIdx.x; i < N_RES; i += 256) msk[i] = 0.0f;
    __syncthreads();
    const unsigned long long* mb = mi64 + (size_t)b * V_PTS;
    for (int v = threadIdx.x; v < V_PTS; v += 256)
        msk[(unsigned int)mb[v]] = 1.0f;
    __syncthreads();

    const int q = threadIdx.x & 31;
    const int s = threadIdx.x >> 5;
    const int n0 = seg * (N_RES / SEGS);
    const float4* fb4 = (const float4*)(feats + ((size_t)b * N_RES + n0) * H_DIM);

    float4 acc = make_float4(0.f, 0.f, 0.f, 0.f);
#pragma unroll
    for (int n = 0; n < N_RES / SEGS / 8; ++n) {
        const int nn = s + n * 8;
        const float m = msk[n0 + nn];
        const float4 f = fb4[(size_t)nn * 32 + q];
        acc.x = fmaf(f.x, m, acc.x);
        acc.y = fmaf(f.y, m, acc.y);
        acc.z = fmaf(f.z, m, acc.z);
        acc.w = fmaf(f.w, m, acc.w);
    }
    red[s][q] = acc;
    __syncthreads();
    if (s == 0) {
        float4 t = acc;
#pragma unroll
        for (int i = 1; i < 8; ++i) {
            t.x += red[i][q].x; t.y += red[i][q].y;
            t.z += red[i][q].z; t.w += red[i][q].w;
        }
        ((float4*)partial)[((size_t)b * SEGS + seg) * 32 + q] = t;
    }
}

// ---------------------------------------------------------------------------
// Kernel 3: per-graph block — reduce 16 seg partials -> pooled[H], then
// relu(pooled@W1+b1)@W2+b2 -> out[b][7]. 16 blocks x 128 threads.
// (Round-1 lesson: last-block-done fusion costs ~19 µs via device-scope
// threadfence on non-coherent XCD L2s. Separate tiny launch is cheaper.)
// ---------------------------------------------------------------------------
__global__ __launch_bounds__(128) void k_mlp(const float* __restrict__ partial,
                                             const float* __restrict__ W1,
                                             const float* __restrict__ b1,
                                             const float* __restrict__ W2,
                                             const float* __restrict__ b2,
                                             float* __restrict__ out) {
    __shared__ float pooled[H_DIM];
    __shared__ float h1[H_DIM];
    const int b = blockIdx.x;
    const int j = threadIdx.x;

    float s = 0.0f;
#pragma unroll
    for (int g = 0; g < SEGS; ++g)
        s += partial[((size_t)b * SEGS + g) * H_DIM + j];
    pooled[j] = s;
    __syncthreads();

    float acc = b1[j];
#pragma unroll 8
    for (int hh = 0; hh < H_DIM; ++hh)
        acc = fmaf(pooled[hh], W1[hh * H_DIM + j], acc);
    h1[j] = fmaxf(acc, 0.0f);
    __syncthreads();

    if (j < C_OUT) {
        float o = b2[j];
#pragma unroll 8
        for (int hh = 0; hh < H_DIM; ++hh)
            o = fmaf(h1[hh], W2[hh * C_OUT + j], o);
        out[(size_t)b * C_OUT + j] = o;
    }
}

extern "C" void kernel_launch(void* const* d_in, const int* in_sizes, int n_in,
                              void* d_out, int out_size, void* d_ws, size_t ws_size,
                              hipStream_t stream) {
    const float* verts  = (const float*)d_in[0];   // [B,V,3]
    const float* coords = (const float*)d_in[1];   // [B,N,3]
    const float* feats  = (const float*)d_in[2];   // [B,N,H]
    const float* W1     = (const float*)d_in[3];   // [H,H]
    const float* b1     = (const float*)d_in[4];   // [H]
    const float* W2     = (const float*)d_in[5];   // [H,C_OUT]
    const float* b2     = (const float*)d_in[6];   // [C_OUT]
    float* out = (float*)d_out;                    // [B,C_OUT]

    const size_t part_bytes = (size_t)B_GR * NSPLIT * V_PTS * 8;   // 16 MB
    const size_t msk_bytes  = (size_t)B_GR * N_RES * 4;            // 128 KB
    const size_t pp_bytes   = (size_t)B_GR * SEGS * H_DIM * 4;     // 128 KB

    if (ws_size >= part_bytes + msk_bytes + pp_bytes) {
        // ---- store + merge path (no device atomics) ----
        unsigned long long* part = (unsigned long long*)d_ws;
        float* msk     = (float*)((char*)d_ws + part_bytes);
        float* partial = (float*)((char*)d_ws + part_bytes + msk_bytes);

        hipMemsetAsync(msk, 0, msk_bytes, stream);                 // graph-legal
        k_argmin_st<<<B_GR * VBLKS * NSPLIT, 256, 0, stream>>>(verts, coords, part);
        k_merge    <<<B_GR * V_PTS / 256,    256, 0, stream>>>(part, msk);
        k_pool_m   <<<B_GR * SEGS,           256, 0, stream>>>(msk, feats, partial);
        k_mlp      <<<B_GR,                  128, 0, stream>>>(partial, W1, b1, W2, b2, out);
    } else {
        // ---- fallback: round-0 atomicMin path ----
        unsigned long long* mi64 = (unsigned long long*)d_ws;              // 1 MB
        float* partial = (float*)((char*)d_ws + (size_t)B_GR * V_PTS * 8); // 128 KB

        hipMemsetAsync(mi64, 0xFF, (size_t)B_GR * V_PTS * 8, stream);
        k_argmin_at<<<B_GR * VBLKS * NSPLIT, 256, 0, stream>>>(verts, coords, mi64);
        k_pool_at  <<<B_GR * SEGS,           256, 0, stream>>>(mi64, feats, partial);
        k_mlp      <<<B_GR,                  128, 0, stream>>>(partial, W1, b1, W2, b2, out);
    }
}

// Round 4
// 144.583 us; speedup vs baseline: 1.2001x; 1.0124x over previous
//
#include <hip/hip_runtime.h>
#include <hip/hip_bf16.h>

// Problem constants (fixed by the reference): B=16, V=8192, N=2048, H=128, C_OUT=7
#define B_GR   16
#define V_PTS  8192
#define N_RES  2048
#define H_DIM  128
#define C_OUT  7
#define SEGS   16            // pool kernel: residue segments per graph (128 residues each)

// argmin decomposition
#define NSPLIT 16                    // residue splits per graph
#define NL     (N_RES / NSPLIT)      // 128 residues per block
#define VPT    16                    // vertices per thread (16 independent FMA chains)
#define VBLK   (256 * VPT)           // 4096 vertices per block
#define VBLKS  (V_PTS / VBLK)        // 2 vertex-blocks per graph
// grid = B * VBLKS * NSPLIT = 16*2*16 = 512 blocks -> 2 blocks/CU, 8 waves/CU.
// Ledger: r1: v_pk_*_f32 NOT double-rate on CDNA4. r2: occupancy 26->47% left
// dur flat at VALUBusy~80% -> issue-bound, not latency-bound; VPT=4 (more
// overhead/pair) regressed. r3: removing atomicMin changed nothing -> atomics
// were free; kernel is pure VALU-issue (10 mandatory VALU/pair = 34 µs ideal).
// r4 lever: amortize per-n overhead over 2x pairs (VPT=16) + slim merge stream.

// ---------------------------------------------------------------------------
// Kernel 1 (store path): partial nearest-residue argmin over a 128-residue
// slice, 16 vertices per thread. Bit-exact replication of the reference fp32
// sequence:
//   d = fadd( fma(-2, dot, vsq), csq ),  dot = fadd(fadd(x*cx, y*cy), z*cz)
// (fma(-2,dot,vsq) == RN(vsq - 2*dot) exactly since 2*dot is exact.)
// Per-split winner stored as (key u32 = monotone-flipped d bits, idx u8 =
// split-local argmin). Equal d within a split keeps first n (strict <);
// cross-split ties resolved in k_merge by ascending split order == smallest
// global index, matching np.argmin first-occurrence. d == -0.0 impossible
// (csq >= +0), so the flip transform's -0<+0 quirk never triggers.
// ---------------------------------------------------------------------------
__global__ __launch_bounds__(256, 2) void k_argmin_st(const float* __restrict__ verts,
                                                      const float* __restrict__ coords,
                                                      unsigned int* __restrict__ pkey,
                                                      unsigned char* __restrict__ pidx) {
    __shared__ float4 sc[NL];                          // 2 KB
    const int b  = blockIdx.x / (VBLKS * NSPLIT);
    const int r  = blockIdx.x % (VBLKS * NSPLIT);
    const int vb = r / NSPLIT;
    const int ns = r % NSPLIT;

    const float* cbase = coords + ((size_t)b * N_RES + ns * NL) * 3;
    if (threadIdx.x < NL) {
        const int i = threadIdx.x;
        float x = cbase[i * 3 + 0];
        float y = cbase[i * 3 + 1];
        float z = cbase[i * 3 + 2];
        float csq = __fadd_rn(__fadd_rn(__fmul_rn(x, x), __fmul_rn(y, y)), __fmul_rn(z, z));
        sc[i] = make_float4(x, y, z, csq);
    }
    __syncthreads();

    const int vbase = vb * VBLK + threadIdx.x;         // vertex index within graph
    const float* vp = verts + (size_t)b * V_PTS * 3;

    float vx[VPT], vy[VPT], vz[VPT], vsq[VPT], best[VPT];
    int bi[VPT];
#pragma unroll
    for (int k = 0; k < VPT; ++k) {
        const int v = vbase + k * 256;
        vx[k] = vp[v * 3 + 0];
        vy[k] = vp[v * 3 + 1];
        vz[k] = vp[v * 3 + 2];
        vsq[k] = __fadd_rn(__fadd_rn(__fmul_rn(vx[k], vx[k]), __fmul_rn(vy[k], vy[k])),
                           __fmul_rn(vz[k], vz[k]));
        best[k] = 3.402823466e+38f;
        bi[k] = 0;
    }

    // unroll 2: n stays a uniform (SGPR) value -> cndmask takes it directly,
    // and the two ds_read_b128s batch ahead of their waits. Inner body:
    // 2*16*10 = 320 VALU per 2 LDS reads -> ~98% VALU instruction density.
#pragma unroll 2
    for (int n = 0; n < NL; ++n) {
        const float4 c = sc[n];
#pragma unroll
        for (int k = 0; k < VPT; ++k) {
            float dot = __fadd_rn(__fadd_rn(__fmul_rn(vx[k], c.x), __fmul_rn(vy[k], c.y)),
                                  __fmul_rn(vz[k], c.z));
            float d = __fadd_rn(fmaf(-2.0f, dot, vsq[k]), c.w);
            bool m = d < best[k];                      // strict <: first index wins
            best[k] = m ? d : best[k];
            bi[k]   = m ? n : bi[k];
        }
    }

    unsigned int*  kb = pkey + ((size_t)(b * NSPLIT + ns)) * V_PTS + vbase;
    unsigned char* ib = pidx + ((size_t)(b * NSPLIT + ns)) * V_PTS + vbase;
#pragma unroll
    for (int k = 0; k < VPT; ++k) {
        unsigned int bits = __float_as_uint(best[k]);
        unsigned int key  = bits ^ (unsigned int)(((int)bits >> 31) | 0x80000000);
        kb[k * 256] = key;                             // plain coalesced stores
        ib[k * 256] = (unsigned char)bi[k];            // NL=128 fits u8
    }
}

// ---------------------------------------------------------------------------
// Kernel 1b (merge): per-vertex min over the 16 per-split key candidates
// (ascending strict < keeps the earliest split == smallest global index on
// ties), fetch that split's local idx byte, scatter 1.0f into the global hit
// mask (race-benign). 512 blocks x 256 threads; 16 coalesced u32 loads.
// ---------------------------------------------------------------------------
__global__ __launch_bounds__(256) void k_merge(const unsigned int* __restrict__ pkey,
                                               const unsigned char* __restrict__ pidx,
                                               float* __restrict__ msk) {
    const int gv = blockIdx.x * 256 + threadIdx.x;     // 0 .. B*V-1
    const int b  = gv >> 13;                           // / V_PTS
    const int v  = gv & (V_PTS - 1);

    const unsigned int* p = pkey + (size_t)b * NSPLIT * V_PTS + v;
    unsigned int ck[NSPLIT];
#pragma unroll
    for (int s = 0; s < NSPLIT; ++s)                   // batch all loads first
        ck[s] = p[(size_t)s * V_PTS];
    unsigned int bk = ck[0];
    int bs = 0;
#pragma unroll
    for (int s = 1; s < NSPLIT; ++s) {
        bool m = ck[s] < bk;                           // strict <: earliest split wins
        bk = m ? ck[s] : bk;
        bs = m ? s : bs;
    }
    const unsigned int li =
        pidx[((size_t)b * NSPLIT + bs) * V_PTS + v];
    msk[b * N_RES + bs * NL + li] = 1.0f;              // global residue index
}

// ---------------------------------------------------------------------------
// Kernel 2 (store path): masked-sum a 128-residue slice of feats with float4
// loads; mask slice staged from the tiny global msk array (512 B).
// Grid: B*SEGS = 256 blocks, 256 threads: lane-quad q=tid&31 covers H=128 as
// float4; slice s=tid>>5 gives 8-way n-parallelism, LDS-reduced at the end.
// ---------------------------------------------------------------------------
__global__ __launch_bounds__(256) void k_pool_m(const float* __restrict__ msk,
                                                const float* __restrict__ feats,
                                                float* __restrict__ partial) {
    __shared__ float sm[NL];                            // 512 B mask slice
    __shared__ float4 red[8][32];
    const int b   = blockIdx.x >> 4;
    const int seg = blockIdx.x & (SEGS - 1);
    const int n0  = seg * (N_RES / SEGS);               // N_RES/SEGS == NL == 128

    if (threadIdx.x < NL) sm[threadIdx.x] = msk[b * N_RES + n0 + threadIdx.x];
    __syncthreads();

    const int q = threadIdx.x & 31;                     // float4 column (h = 4q..4q+3)
    const int s = threadIdx.x >> 5;                     // n-slice 0..7
    const float4* fb4 = (const float4*)(feats + ((size_t)b * N_RES + n0) * H_DIM);

    float4 acc = make_float4(0.f, 0.f, 0.f, 0.f);
#pragma unroll
    for (int n = 0; n < N_RES / SEGS / 8; ++n) {
        const int nn = s + n * 8;
        const float m = sm[nn];
        const float4 f = fb4[(size_t)nn * 32 + q];
        acc.x = fmaf(f.x, m, acc.x);
        acc.y = fmaf(f.y, m, acc.y);
        acc.z = fmaf(f.z, m, acc.z);
        acc.w = fmaf(f.w, m, acc.w);
    }
    red[s][q] = acc;
    __syncthreads();

    if (s == 0) {
        float4 t = acc;
#pragma unroll
        for (int i = 1; i < 8; ++i) {
            t.x += red[i][q].x; t.y += red[i][q].y;
            t.z += red[i][q].z; t.w += red[i][q].w;
        }
        ((float4*)partial)[((size_t)b * SEGS + seg) * 32 + q] = t;
    }
}

// ---------------------------------------------------------------------------
// Fallback path (small workspace): round-0 atomicMin kernels, verbatim.
// ---------------------------------------------------------------------------
#define FVPT   8
#define FVBLK  (256 * FVPT)
#define FVBLKS (V_PTS / FVBLK)
__global__ __launch_bounds__(256, 4) void k_argmin_at(const float* __restrict__ verts,
                                                      const float* __restrict__ coords,
                                                      unsigned long long* __restrict__ mi64) {
    __shared__ float4 sc[NL];
    const int b  = blockIdx.x / (FVBLKS * NSPLIT);
    const int r  = blockIdx.x % (FVBLKS * NSPLIT);
    const int vb = r / NSPLIT;
    const int ns = r % NSPLIT;

    const float* cbase = coords + ((size_t)b * N_RES + ns * NL) * 3;
    if (threadIdx.x < NL) {
        const int i = threadIdx.x;
        float x = cbase[i * 3 + 0];
        float y = cbase[i * 3 + 1];
        float z = cbase[i * 3 + 2];
        float csq = __fadd_rn(__fadd_rn(__fmul_rn(x, x), __fmul_rn(y, y)), __fmul_rn(z, z));
        sc[i] = make_float4(x, y, z, csq);
    }
    __syncthreads();

    const int vbase = vb * FVBLK + threadIdx.x;
    const float* vp = verts + (size_t)b * V_PTS * 3;

    float vx[FVPT], vy[FVPT], vz[FVPT], vsq[FVPT], best[FVPT];
    int bi[FVPT];
#pragma unroll
    for (int k = 0; k < FVPT; ++k) {
        const int v = vbase + k * 256;
        vx[k] = vp[v * 3 + 0];
        vy[k] = vp[v * 3 + 1];
        vz[k] = vp[v * 3 + 2];
        vsq[k] = __fadd_rn(__fadd_rn(__fmul_rn(vx[k], vx[k]), __fmul_rn(vy[k], vy[k])),
                           __fmul_rn(vz[k], vz[k]));
        best[k] = 3.402823466e+38f;
        bi[k] = 0;
    }
#pragma unroll 2
    for (int n = 0; n < NL; ++n) {
        const float4 c = sc[n];
#pragma unroll
        for (int k = 0; k < FVPT; ++k) {
            float dot = __fadd_rn(__fadd_rn(__fmul_rn(vx[k], c.x), __fmul_rn(vy[k], c.y)),
                                  __fmul_rn(vz[k], c.z));
            float d = __fadd_rn(fmaf(-2.0f, dot, vsq[k]), c.w);
            bool m = d < best[k];
            best[k] = m ? d : best[k];
            bi[k]   = m ? n : bi[k];
        }
    }
#pragma unroll
    for (int k = 0; k < FVPT; ++k) {
        unsigned int bits = __float_as_uint(best[k]);
        unsigned int key  = bits ^ (unsigned int)(((int)bits >> 31) | 0x80000000);
        unsigned long long packed =
            ((unsigned long long)key << 32) | (unsigned int)(ns * NL + bi[k]);
        atomicMin(&mi64[(size_t)b * V_PTS + vbase + k * 256], packed);
    }
}

__global__ __launch_bounds__(256) void k_pool_at(const unsigned long long* __restrict__ mi64,
                                                 const float* __restrict__ feats,
                                                 float* __restrict__ partial) {
    __shared__ float msk[N_RES];
    __shared__ float4 red[8][32];
    const int b   = blockIdx.x >> 4;
    const int seg = blockIdx.x & (SEGS - 1);

    for (int i = threadIdx.x; i < N_RES; i += 256) msk[i] = 0.0f;
    __syncthreads();
    const unsigned long long* mb = mi64 + (size_t)b * V_PTS;
    for (int v = threadIdx.x; v < V_PTS; v += 256)
        msk[(unsigned int)mb[v]] = 1.0f;
    __syncthreads();

    const int q = threadIdx.x & 31;
    const int s = threadIdx.x >> 5;
    const int n0 = seg * (N_RES / SEGS);
    const float4* fb4 = (const float4*)(feats + ((size_t)b * N_RES + n0) * H_DIM);

    float4 acc = make_float4(0.f, 0.f, 0.f, 0.f);
#pragma unroll
    for (int n = 0; n < N_RES / SEGS / 8; ++n) {
        const int nn = s + n * 8;
        const float m = msk[n0 + nn];
        const float4 f = fb4[(size_t)nn * 32 + q];
        acc.x = fmaf(f.x, m, acc.x);
        acc.y = fmaf(f.y, m, acc.y);
        acc.z = fmaf(f.z, m, acc.z);
        acc.w = fmaf(f.w, m, acc.w);
    }
    red[s][q] = acc;
    __syncthreads();
    if (s == 0) {
        float4 t = acc;
#pragma unroll
        for (int i = 1; i < 8; ++i) {
            t.x += red[i][q].x; t.y += red[i][q].y;
            t.z += red[i][q].z; t.w += red[i][q].w;
        }
        ((float4*)partial)[((size_t)b * SEGS + seg) * 32 + q] = t;
    }
}

// ---------------------------------------------------------------------------
// Kernel 3: per-graph block — reduce 16 seg partials -> pooled[H], then
// relu(pooled@W1+b1)@W2+b2 -> out[b][7]. 16 blocks x 128 threads.
// (r1 lesson: last-block-done fusion costs ~19 µs via device-scope
// threadfence on non-coherent XCD L2s. Separate tiny launch is cheaper.)
// ---------------------------------------------------------------------------
__global__ __launch_bounds__(128) void k_mlp(const float* __restrict__ partial,
                                             const float* __restrict__ W1,
                                             const float* __restrict__ b1,
                                             const float* __restrict__ W2,
                                             const float* __restrict__ b2,
                                             float* __restrict__ out) {
    __shared__ float pooled[H_DIM];
    __shared__ float h1[H_DIM];
    const int b = blockIdx.x;
    const int j = threadIdx.x;

    float s = 0.0f;
#pragma unroll
    for (int g = 0; g < SEGS; ++g)
        s += partial[((size_t)b * SEGS + g) * H_DIM + j];
    pooled[j] = s;
    __syncthreads();

    float acc = b1[j];
#pragma unroll 8
    for (int hh = 0; hh < H_DIM; ++hh)
        acc = fmaf(pooled[hh], W1[hh * H_DIM + j], acc);
    h1[j] = fmaxf(acc, 0.0f);
    __syncthreads();

    if (j < C_OUT) {
        float o = b2[j];
#pragma unroll 8
        for (int hh = 0; hh < H_DIM; ++hh)
            o = fmaf(h1[hh], W2[hh * C_OUT + j], o);
        out[(size_t)b * C_OUT + j] = o;
    }
}

extern "C" void kernel_launch(void* const* d_in, const int* in_sizes, int n_in,
                              void* d_out, int out_size, void* d_ws, size_t ws_size,
                              hipStream_t stream) {
    const float* verts  = (const float*)d_in[0];   // [B,V,3]
    const float* coords = (const float*)d_in[1];   // [B,N,3]
    const float* feats  = (const float*)d_in[2];   // [B,N,H]
    const float* W1     = (const float*)d_in[3];   // [H,H]
    const float* b1     = (const float*)d_in[4];   // [H]
    const float* W2     = (const float*)d_in[5];   // [H,C_OUT]
    const float* b2     = (const float*)d_in[6];   // [C_OUT]
    float* out = (float*)d_out;                    // [B,C_OUT]

    const size_t key_bytes = (size_t)B_GR * NSPLIT * V_PTS * 4;    // 8 MB
    const size_t idx_bytes = (size_t)B_GR * NSPLIT * V_PTS;        // 2 MB
    const size_t msk_bytes = (size_t)B_GR * N_RES * 4;             // 128 KB
    const size_t pp_bytes  = (size_t)B_GR * SEGS * H_DIM * 4;      // 128 KB

    if (ws_size >= key_bytes + idx_bytes + msk_bytes + pp_bytes) {
        // ---- store + merge path (no device atomics) ----
        unsigned int*  pkey = (unsigned int*)d_ws;
        unsigned char* pidx = (unsigned char*)d_ws + key_bytes;
        float* msk     = (float*)((char*)d_ws + key_bytes + idx_bytes);
        float* partial = (float*)((char*)d_ws + key_bytes + idx_bytes + msk_bytes);

        hipMemsetAsync(msk, 0, msk_bytes, stream);                 // graph-legal
        k_argmin_st<<<B_GR * VBLKS * NSPLIT, 256, 0, stream>>>(verts, coords, pkey, pidx);
        k_merge    <<<B_GR * V_PTS / 256,    256, 0, stream>>>(pkey, pidx, msk);
        k_pool_m   <<<B_GR * SEGS,           256, 0, stream>>>(msk, feats, partial);
        k_mlp      <<<B_GR,                  128, 0, stream>>>(partial, W1, b1, W2, b2, out);
    } else {
        // ---- fallback: round-0 atomicMin path ----
        unsigned long long* mi64 = (unsigned long long*)d_ws;              // 1 MB
        float* partial = (float*)((char*)d_ws + (size_t)B_GR * V_PTS * 8); // 128 KB

        hipMemsetAsync(mi64, 0xFF, (size_t)B_GR * V_PTS * 8, stream);
        k_argmin_at<<<B_GR * FVBLKS * NSPLIT, 256, 0, stream>>>(verts, coords, mi64);
        k_pool_at  <<<B_GR * SEGS,            256, 0, stream>>>(mi64, feats, partial);
        k_mlp      <<<B_GR,                   128, 0, stream>>>(partial, W1, b1, W2, b2, out);
    }
}